// Round 1
// baseline (497.833 us; speedup 1.0000x reference)
//
#include <hip/hip_runtime.h>

// GAT on MI355X. Pipeline:
//  K1 gemm_xh   : xh = x @ lin_w.T            [8192,256] f32, 64x64 tiled
//  K2 att_cnt   : a_src/a_dst per (node,head); cnt[n]=1 (self-loop)
//  K3 degree    : cnt[dst]++ over E edges (int atomics)
//  K4 scan      : rowptr = exclusive prefix(cnt); wpos = rowptr copy
//  K5 scatter   : CSR bucket edges (+self loops) by dst
//  K6 agg       : per dst node: softmax weights (no max-sub needed, logits O(4))
//                 + weighted gather of xh[src] -> out_flat = agg + bias
//  K7 final_dot : y partials = out_flat . out_w[c,:]  (268 MB stream, HBM-bound)
//  K8 finalize  : reduce partials + bias + softmax -> d_out[32]

namespace {
constexpr int  kN    = 8192;
constexpr int  kE    = 262144;
constexpr int  kTotE = kE + kN;          // 270336 (self loops appended)
constexpr long kK    = 2097152;          // N * H * C
constexpr int  kNBF  = 1024;             // final-dot blocks
constexpr int  kChunk = (int)(kK / kNBF);// 2048 k per block (exact)
}

// ---------------- K1: xh = x @ lin_w^T  (M=8192, N=256, K=256) ----------------
__global__ __launch_bounds__(256) void gemm_xh(const float* __restrict__ x,
                                               const float* __restrict__ lw,
                                               float* __restrict__ xh) {
  __shared__ float As[16][68];  // [k][row], pad 68 -> 16B-aligned float4 rows, low conflicts
  __shared__ float Bs[16][68];  // [k][col]
  const int t  = threadIdx.x;
  const int tx = t & 15, ty = t >> 4;
  const int rowBase = blockIdx.x * 64;
  const int colBase = blockIdx.y * 64;
  const int lr = t >> 2;         // 0..63 staging row/col
  const int lk = (t & 3) * 4;    // k offset {0,4,8,12}

  float acc[4][4] = {};
  for (int kc = 0; kc < 256; kc += 16) {
    float4 av = *(const float4*)(x  + (long)(rowBase + lr) * 256 + kc + lk);
    float4 bv = *(const float4*)(lw + (long)(colBase + lr) * 256 + kc + lk);
    __syncthreads();  // protect previous-iter LDS reads
    As[lk + 0][lr] = av.x; As[lk + 1][lr] = av.y; As[lk + 2][lr] = av.z; As[lk + 3][lr] = av.w;
    Bs[lk + 0][lr] = bv.x; Bs[lk + 1][lr] = bv.y; Bs[lk + 2][lr] = bv.z; Bs[lk + 3][lr] = bv.w;
    __syncthreads();
#pragma unroll
    for (int k = 0; k < 16; k++) {
      float4 a4 = *(const float4*)(&As[k][ty * 4]);
      float4 b4 = *(const float4*)(&Bs[k][tx * 4]);
      float aa[4] = {a4.x, a4.y, a4.z, a4.w};
      float bb[4] = {b4.x, b4.y, b4.z, b4.w};
#pragma unroll
      for (int i = 0; i < 4; i++)
#pragma unroll
        for (int j = 0; j < 4; j++) acc[i][j] += aa[i] * bb[j];
    }
  }
#pragma unroll
  for (int i = 0; i < 4; i++) {
    float4 o = make_float4(acc[i][0], acc[i][1], acc[i][2], acc[i][3]);
    *(float4*)(xh + (long)(rowBase + ty * 4 + i) * 256 + colBase + tx * 4) = o;
  }
}

// ---------------- K2: per-(node,head) attention dots + cnt init ----------------
__global__ __launch_bounds__(256) void att_cnt(const float* __restrict__ xh,
                                               const float* __restrict__ att_s,
                                               const float* __restrict__ att_d,
                                               float* __restrict__ a_src,
                                               float* __restrict__ a_dst,
                                               int* __restrict__ cnt) {
  const int n = blockIdx.x, t = threadIdx.x;  // t = h*32 + c
  float v = xh[(long)n * 256 + t];
  float s = v * att_s[t];
  float d = v * att_d[t];
#pragma unroll
  for (int off = 16; off; off >>= 1) {
    s += __shfl_down(s, off, 32);
    d += __shfl_down(d, off, 32);
  }
  if ((t & 31) == 0) {
    a_src[n * 8 + (t >> 5)] = s;
    a_dst[n * 8 + (t >> 5)] = d;
  }
  if (t == 0) cnt[n] = 1;  // self-loop
}

// ---------------- K3: in-degree histogram ----------------
__global__ __launch_bounds__(256) void degree(const int* __restrict__ ei, int* __restrict__ cnt) {
  int idx = blockIdx.x * 256 + threadIdx.x;
  if (idx < kE) atomicAdd(&cnt[ei[kE + idx]], 1);  // ei[1][e] = dst
}

// ---------------- K4: single-block exclusive scan of 8192 counts ----------------
__global__ __launch_bounds__(1024) void scan_cnt(const int* __restrict__ cnt,
                                                 int* __restrict__ rowptr,
                                                 int* __restrict__ wpos) {
  __shared__ int s[1024];
  const int t = threadIdx.x;
  int v[8]; int sum = 0;
#pragma unroll
  for (int q = 0; q < 8; q++) { v[q] = cnt[t * 8 + q]; sum += v[q]; }
  s[t] = sum;
  __syncthreads();
  for (int off = 1; off < 1024; off <<= 1) {
    int add = (t >= off) ? s[t - off] : 0;
    __syncthreads();
    s[t] += add;
    __syncthreads();
  }
  int excl = s[t] - sum;  // exclusive prefix for this thread's base
#pragma unroll
  for (int q = 0; q < 8; q++) {
    rowptr[t * 8 + q] = excl;
    wpos[t * 8 + q]   = excl;
    excl += v[q];
  }
  if (t == 1023) rowptr[kN] = s[1023];
}

// ---------------- K5: bucket edges (+ self loops) by dst ----------------
__global__ __launch_bounds__(256) void scatter_csr(const int* __restrict__ ei,
                                                   int* __restrict__ wpos,
                                                   int* __restrict__ csr) {
  int idx = blockIdx.x * 256 + threadIdx.x;
  if (idx >= kTotE) return;
  int s, d;
  if (idx < kE) { s = ei[idx]; d = ei[kE + idx]; }
  else          { s = idx - kE; d = s; }
  int pos = atomicAdd(&wpos[d], 1);
  csr[pos] = s;
}

// ---------------- K6: segment softmax + weighted aggregation (gather) ----------------
__global__ __launch_bounds__(256) void agg_kernel(const float* __restrict__ xh,
                                                  const float* __restrict__ a_src,
                                                  const float* __restrict__ a_dst,
                                                  const int* __restrict__ rowptr,
                                                  const int* __restrict__ csr,
                                                  const float* __restrict__ bias,
                                                  float* __restrict__ out_flat) {
  const int i = blockIdx.x, t = threadIdx.x, h = t >> 5;
  const float ad = a_dst[i * 8 + h];
  const int beg = rowptr[i], end = rowptr[i + 1];
  float acc = 0.f, den = 0.f;
  for (int j = beg; j < end; j++) {
    int s = csr[j];
    float e = a_src[s * 8 + h] + ad;
    e = (e > 0.f) ? e : 0.2f * e;       // leaky_relu(0.2)
    float w = __expf(e);                // no max-subtraction needed: |e| <~ 5
    den += w;
    acc += w * xh[(long)s * 256 + t];
  }
  out_flat[(long)i * 256 + t] = acc / den + bias[t];
}

// ---------------- K7: y partials = out_flat . out_w rows (268 MB stream) ----------------
__global__ __launch_bounds__(256) void final_dot(const float* __restrict__ of,
                                                 const float* __restrict__ w,
                                                 float* __restrict__ part) {
  const int t = threadIdx.x, b = blockIdx.x;
  float acc[32];
#pragma unroll
  for (int c = 0; c < 32; c++) acc[c] = 0.f;
#pragma unroll
  for (int it = 0; it < kChunk / 1024; it++) {
    const long k = (long)b * kChunk + it * 1024 + t * 4;
    float4 f = *(const float4*)(of + k);
#pragma unroll
    for (int c = 0; c < 32; c++) {
      float4 wv = *(const float4*)(w + (long)c * kK + k);
      acc[c] += wv.x * f.x + wv.y * f.y + wv.z * f.z + wv.w * f.w;
    }
  }
  // wave reduce each of the 32 accumulators
#pragma unroll
  for (int c = 0; c < 32; c++) {
    float v = acc[c];
    v += __shfl_down(v, 32, 64);
    v += __shfl_down(v, 16, 64);
    v += __shfl_down(v, 8, 64);
    v += __shfl_down(v, 4, 64);
    v += __shfl_down(v, 2, 64);
    v += __shfl_down(v, 1, 64);
    acc[c] = v;
  }
  __shared__ float s[4][32];
  const int lane = t & 63, wid = t >> 6;
  if (lane == 0) {
#pragma unroll
    for (int c = 0; c < 32; c++) s[wid][c] = acc[c];
  }
  __syncthreads();
  if (t < 32) part[b * 32 + t] = s[0][t] + s[1][t] + s[2][t] + s[3][t];
}

// ---------------- K8: reduce partials + bias + softmax ----------------
__global__ __launch_bounds__(1024) void finalize(const float* __restrict__ part,
                                                 const float* __restrict__ ob,
                                                 float* __restrict__ out) {
  __shared__ float s[32][33];
  const int t = threadIdx.x;
  const int c = t & 31, r = t >> 5;
  float sum = 0.f;
  for (int i = r; i < kNBF; i += 32) sum += part[i * 32 + c];
  s[c][r] = sum;
  __syncthreads();
  if (t < 32) {
    float y = ob[t];
#pragma unroll
    for (int r2 = 0; r2 < 32; r2++) y += s[t][r2];
    float m = y;
#pragma unroll
    for (int off = 16; off; off >>= 1) m = fmaxf(m, __shfl_xor(m, off, 32));
    float e = __expf(y - m);
    float d = e;
#pragma unroll
    for (int off = 16; off; off >>= 1) d += __shfl_xor(d, off, 32);
    out[t] = e / d;
  }
}

extern "C" void kernel_launch(void* const* d_in, const int* in_sizes, int n_in,
                              void* d_out, int out_size, void* d_ws, size_t ws_size,
                              hipStream_t stream) {
  (void)in_sizes; (void)n_in; (void)out_size; (void)ws_size;
  const float* x     = (const float*)d_in[0];
  const int*   ei    = (const int*)  d_in[1];
  const float* lin_w = (const float*)d_in[2];
  const float* att_s = (const float*)d_in[3];
  const float* att_d = (const float*)d_in[4];
  const float* bias  = (const float*)d_in[5];
  const float* out_w = (const float*)d_in[6];
  const float* out_b = (const float*)d_in[7];
  float* out = (float*)d_out;

  // workspace layout (~17.8 MB)
  float* xh       = (float*)d_ws;
  float* out_flat = xh + kK;
  float* a_src    = out_flat + kK;
  float* a_dst    = a_src + kN * 8;
  float* part     = a_dst + kN * 8;
  int*   cnt      = (int*)(part + kNBF * 32);
  int*   rowptr   = cnt + kN;
  int*   wpos     = rowptr + (kN + 1);
  int*   csr      = wpos + kN;

  gemm_xh   <<<dim3(128, 4), 256, 0, stream>>>(x, lin_w, xh);
  att_cnt   <<<kN, 256, 0, stream>>>(xh, att_s, att_d, a_src, a_dst, cnt);
  degree    <<<kE / 256, 256, 0, stream>>>(ei, cnt);
  scan_cnt  <<<1, 1024, 0, stream>>>(cnt, rowptr, wpos);
  scatter_csr<<<kTotE / 256, 256, 0, stream>>>(ei, wpos, csr);
  agg_kernel<<<kN, 256, 0, stream>>>(xh, a_src, a_dst, rowptr, csr, bias, out_flat);
  final_dot <<<kNBF, 256, 0, stream>>>(out_flat, out_w, part);
  finalize  <<<1, 1024, 0, stream>>>(part, out_b, out);
}

// Round 2
// 493.833 us; speedup vs baseline: 1.0081x; 1.0081x over previous
//
#include <hip/hip_runtime.h>

// GAT on MI355X. Pipeline:
//  K1 gemm_xh    : xh = x @ lin_w.T            [8192,256] f32, 64x64 tiled
//  K2 att_cnt    : a_src/a_dst per (node,head); cnt[n]=1 (self-loop)
//  K3 degree     : cnt[dst]++ over E edges (int atomics)
//  K4 scan       : rowptr = exclusive prefix(cnt); wpos = rowptr copy
//  K5 scatter    : CSR bucket edges (+self loops) by dst; ALSO computes the
//                  8 per-head exp(leakyrelu) weights per edge (once, not 256x)
//  K6 agg        : per dst node: den = sum w, acc = sum w * xh[src] -- gather
//                  loop unrolled x4 for MLP (was the latency-bound MLP=1 loop)
//  K7 final_dot  : y partials = out_flat . out_w[c,:]  (268 MB stream, HBM floor ~43us)
//  K8 finalize   : reduce partials + bias + softmax -> d_out[32]

namespace {
constexpr int  kN    = 8192;
constexpr int  kE    = 262144;
constexpr int  kTotE = kE + kN;          // 270336 (self loops appended)
constexpr long kK    = 2097152;          // N * H * C
constexpr int  kNBF  = 2048;             // final-dot blocks (1024 k each, exact)
}

// ---------------- K1: xh = x @ lin_w^T  (M=8192, N=256, K=256) ----------------
__global__ __launch_bounds__(256) void gemm_xh(const float* __restrict__ x,
                                               const float* __restrict__ lw,
                                               float* __restrict__ xh) {
  __shared__ float As[16][68];
  __shared__ float Bs[16][68];
  const int t  = threadIdx.x;
  const int tx = t & 15, ty = t >> 4;
  const int rowBase = blockIdx.x * 64;
  const int colBase = blockIdx.y * 64;
  const int lr = t >> 2;
  const int lk = (t & 3) * 4;

  float acc[4][4] = {};
  for (int kc = 0; kc < 256; kc += 16) {
    float4 av = *(const float4*)(x  + (long)(rowBase + lr) * 256 + kc + lk);
    float4 bv = *(const float4*)(lw + (long)(colBase + lr) * 256 + kc + lk);
    __syncthreads();
    As[lk + 0][lr] = av.x; As[lk + 1][lr] = av.y; As[lk + 2][lr] = av.z; As[lk + 3][lr] = av.w;
    Bs[lk + 0][lr] = bv.x; Bs[lk + 1][lr] = bv.y; Bs[lk + 2][lr] = bv.z; Bs[lk + 3][lr] = bv.w;
    __syncthreads();
#pragma unroll
    for (int k = 0; k < 16; k++) {
      float4 a4 = *(const float4*)(&As[k][ty * 4]);
      float4 b4 = *(const float4*)(&Bs[k][tx * 4]);
      float aa[4] = {a4.x, a4.y, a4.z, a4.w};
      float bb[4] = {b4.x, b4.y, b4.z, b4.w};
#pragma unroll
      for (int i = 0; i < 4; i++)
#pragma unroll
        for (int j = 0; j < 4; j++) acc[i][j] += aa[i] * bb[j];
    }
  }
#pragma unroll
  for (int i = 0; i < 4; i++) {
    float4 o = make_float4(acc[i][0], acc[i][1], acc[i][2], acc[i][3]);
    *(float4*)(xh + (long)(rowBase + ty * 4 + i) * 256 + colBase + tx * 4) = o;
  }
}

// ---------------- K2: per-(node,head) attention dots + cnt init ----------------
__global__ __launch_bounds__(256) void att_cnt(const float* __restrict__ xh,
                                               const float* __restrict__ att_s,
                                               const float* __restrict__ att_d,
                                               float* __restrict__ a_src,
                                               float* __restrict__ a_dst,
                                               int* __restrict__ cnt) {
  const int n = blockIdx.x, t = threadIdx.x;  // t = h*32 + c
  float v = xh[(long)n * 256 + t];
  float s = v * att_s[t];
  float d = v * att_d[t];
#pragma unroll
  for (int off = 16; off; off >>= 1) {
    s += __shfl_down(s, off, 32);
    d += __shfl_down(d, off, 32);
  }
  if ((t & 31) == 0) {
    a_src[n * 8 + (t >> 5)] = s;
    a_dst[n * 8 + (t >> 5)] = d;
  }
  if (t == 0) cnt[n] = 1;  // self-loop
}

// ---------------- K3: in-degree histogram ----------------
__global__ __launch_bounds__(256) void degree(const int* __restrict__ ei, int* __restrict__ cnt) {
  int idx = blockIdx.x * 256 + threadIdx.x;
  if (idx < kE) atomicAdd(&cnt[ei[kE + idx]], 1);  // ei[1][e] = dst
}

// ---------------- K4: single-block exclusive scan of 8192 counts ----------------
__global__ __launch_bounds__(1024) void scan_cnt(const int* __restrict__ cnt,
                                                 int* __restrict__ rowptr,
                                                 int* __restrict__ wpos) {
  __shared__ int s[1024];
  const int t = threadIdx.x;
  int v[8]; int sum = 0;
#pragma unroll
  for (int q = 0; q < 8; q++) { v[q] = cnt[t * 8 + q]; sum += v[q]; }
  s[t] = sum;
  __syncthreads();
  for (int off = 1; off < 1024; off <<= 1) {
    int add = (t >= off) ? s[t - off] : 0;
    __syncthreads();
    s[t] += add;
    __syncthreads();
  }
  int excl = s[t] - sum;
#pragma unroll
  for (int q = 0; q < 8; q++) {
    rowptr[t * 8 + q] = excl;
    wpos[t * 8 + q]   = excl;
    excl += v[q];
  }
  if (t == 1023) rowptr[kN] = s[1023];
}

// ---------------- K5: bucket edges by dst + per-edge 8-head weights ----------------
__global__ __launch_bounds__(256) void scatter_csr(const int* __restrict__ ei,
                                                   const float* __restrict__ a_src,
                                                   const float* __restrict__ a_dst,
                                                   int* __restrict__ wpos,
                                                   int* __restrict__ csr,
                                                   float* __restrict__ w8) {
  int idx = blockIdx.x * 256 + threadIdx.x;
  if (idx >= kTotE) return;
  int s, d;
  if (idx < kE) { s = ei[idx]; d = ei[kE + idx]; }
  else          { s = idx - kE; d = s; }
  int pos = atomicAdd(&wpos[d], 1);
  csr[pos] = s;
  // 8 head weights, computed ONCE per edge (was 256x redundant in the gather)
  float4 s0 = *(const float4*)(a_src + s * 8);
  float4 s1 = *(const float4*)(a_src + s * 8 + 4);
  float4 d0 = *(const float4*)(a_dst + d * 8);
  float4 d1 = *(const float4*)(a_dst + d * 8 + 4);
  float e[8] = {s0.x + d0.x, s0.y + d0.y, s0.z + d0.z, s0.w + d0.w,
                s1.x + d1.x, s1.y + d1.y, s1.z + d1.z, s1.w + d1.w};
  float w[8];
#pragma unroll
  for (int h = 0; h < 8; h++) {
    float ee = (e[h] > 0.f) ? e[h] : 0.2f * e[h];   // leaky_relu(0.2)
    w[h] = __expf(ee);                              // |e| <~ 5, no max-sub needed
  }
  float4* wp = (float4*)(w8 + (long)pos * 8);
  wp[0] = make_float4(w[0], w[1], w[2], w[3]);
  wp[1] = make_float4(w[4], w[5], w[6], w[7]);
}

// ---------------- K6: weighted gather aggregation, unrolled x4 for MLP ----------------
__global__ __launch_bounds__(256) void agg_kernel(const float* __restrict__ xh,
                                                  const float* __restrict__ w8,
                                                  const int* __restrict__ rowptr,
                                                  const int* __restrict__ csr,
                                                  const float* __restrict__ bias,
                                                  float* __restrict__ out_flat) {
  const int i = blockIdx.x, t = threadIdx.x, h = t >> 5;
  const int beg = rowptr[i], end = rowptr[i + 1];
  float acc = 0.f, den = 0.f;
  int j = beg;
  for (; j + 4 <= end; j += 4) {
    int s0 = csr[j], s1 = csr[j + 1], s2 = csr[j + 2], s3 = csr[j + 3];
    float w0 = w8[(long)(j + 0) * 8 + h];
    float w1 = w8[(long)(j + 1) * 8 + h];
    float w2 = w8[(long)(j + 2) * 8 + h];
    float w3 = w8[(long)(j + 3) * 8 + h];
    float f0 = xh[(long)s0 * 256 + t];
    float f1 = xh[(long)s1 * 256 + t];
    float f2 = xh[(long)s2 * 256 + t];
    float f3 = xh[(long)s3 * 256 + t];
    den += (w0 + w1) + (w2 + w3);
    acc += w0 * f0;
    acc += w1 * f1;
    acc += w2 * f2;
    acc += w3 * f3;
  }
  for (; j < end; j++) {
    int s = csr[j];
    float w = w8[(long)j * 8 + h];
    den += w;
    acc += w * xh[(long)s * 256 + t];
  }
  out_flat[(long)i * 256 + t] = acc / den + bias[t];
}

// ---------------- K7: y partials = out_flat . out_w rows (268 MB stream) ----------------
__global__ __launch_bounds__(256) void final_dot(const float* __restrict__ of,
                                                 const float* __restrict__ w,
                                                 float* __restrict__ part) {
  const int t = threadIdx.x, b = blockIdx.x;
  const long k = (long)b * 1024 + t * 4;
  float4 f = *(const float4*)(of + k);
  float acc[32];
#pragma unroll
  for (int c = 0; c < 32; c++) {
    float4 wv = *(const float4*)(w + (long)c * kK + k);
    acc[c] = wv.x * f.x + wv.y * f.y + wv.z * f.z + wv.w * f.w;
  }
#pragma unroll
  for (int c = 0; c < 32; c++) {
    float v = acc[c];
    v += __shfl_down(v, 32, 64);
    v += __shfl_down(v, 16, 64);
    v += __shfl_down(v, 8, 64);
    v += __shfl_down(v, 4, 64);
    v += __shfl_down(v, 2, 64);
    v += __shfl_down(v, 1, 64);
    acc[c] = v;
  }
  __shared__ float s[4][32];
  const int lane = t & 63, wid = t >> 6;
  if (lane == 0) {
#pragma unroll
    for (int c = 0; c < 32; c++) s[wid][c] = acc[c];
  }
  __syncthreads();
  if (t < 32) part[b * 32 + t] = s[0][t] + s[1][t] + s[2][t] + s[3][t];
}

// ---------------- K8: reduce partials + bias + softmax ----------------
__global__ __launch_bounds__(1024) void finalize(const float* __restrict__ part,
                                                 const float* __restrict__ ob,
                                                 float* __restrict__ out) {
  __shared__ float s[32][33];
  const int t = threadIdx.x;
  const int c = t & 31, r = t >> 5;
  float sum = 0.f;
  for (int i = r; i < kNBF; i += 32) sum += part[i * 32 + c];
  s[c][r] = sum;
  __syncthreads();
  if (t < 32) {
    float y = ob[t];
#pragma unroll
    for (int r2 = 0; r2 < 32; r2++) y += s[t][r2];
    float m = y;
#pragma unroll
    for (int off = 16; off; off >>= 1) m = fmaxf(m, __shfl_xor(m, off, 32));
    float e = __expf(y - m);
    float d = e;
#pragma unroll
    for (int off = 16; off; off >>= 1) d += __shfl_xor(d, off, 32);
    out[t] = e / d;
  }
}

extern "C" void kernel_launch(void* const* d_in, const int* in_sizes, int n_in,
                              void* d_out, int out_size, void* d_ws, size_t ws_size,
                              hipStream_t stream) {
  (void)in_sizes; (void)n_in; (void)out_size; (void)ws_size;
  const float* x     = (const float*)d_in[0];
  const int*   ei    = (const int*)  d_in[1];
  const float* lin_w = (const float*)d_in[2];
  const float* att_s = (const float*)d_in[3];
  const float* att_d = (const float*)d_in[4];
  const float* bias  = (const float*)d_in[5];
  const float* out_w = (const float*)d_in[6];
  const float* out_b = (const float*)d_in[7];
  float* out = (float*)d_out;

  // workspace layout (~27 MB)
  float* xh       = (float*)d_ws;
  float* out_flat = xh + kK;
  float* a_src    = out_flat + kK;
  float* a_dst    = a_src + kN * 8;
  float* part     = a_dst + kN * 8;
  float* w8       = part + (long)kNBF * 32;
  int*   cnt      = (int*)(w8 + (long)kTotE * 8);
  int*   rowptr   = cnt + kN;
  int*   wpos     = rowptr + (kN + 1);
  int*   csr      = wpos + kN;

  gemm_xh    <<<dim3(128, 4), 256, 0, stream>>>(x, lin_w, xh);
  att_cnt    <<<kN, 256, 0, stream>>>(xh, att_s, att_d, a_src, a_dst, cnt);
  degree     <<<kE / 256, 256, 0, stream>>>(ei, cnt);
  scan_cnt   <<<1, 1024, 0, stream>>>(cnt, rowptr, wpos);
  scatter_csr<<<(kTotE + 255) / 256, 256, 0, stream>>>(ei, a_src, a_dst, wpos, csr, w8);
  agg_kernel <<<kN, 256, 0, stream>>>(xh, w8, rowptr, csr, bias, out_flat);
  final_dot  <<<kNBF, 256, 0, stream>>>(out_flat, out_w, part);
  finalize   <<<1, 1024, 0, stream>>>(part, out_b, out);
}

// Round 4
// 458.239 us; speedup vs baseline: 1.0864x; 1.0777x over previous
//
#include <hip/hip_runtime.h>

// GAT on MI355X. Pipeline (7 dispatches + 1 memset):
//  M0 memset     : cnt = 0 (hipMemsetAsync, graph-capturable)
//  K1 gemm_xh    : xh = x @ lin_w.T  [8192,256] f32 64x64 tiled; epilogue also
//                  writes bf16 copy xh_bf (halves agg gather traffic)
//  K2 att_deg    : a_src/a_dst per (node,head)  +  cnt[dst]++ histogram (merged)
//  K3 scan       : rowptr = exclusive prefix(cnt + 1/self-loop); wpos = copy
//  K4 scatter    : CSR bucket edges (+self loops) by dst + per-edge 8-head
//                  exp(leakyrelu) weights (computed once, not 256x)
//  K5 agg        : per dst node: den = sum w, acc = sum w * xh_bf[src]
//                  (bf16 gathers, unroll x8 for MLP; bf16 err ~4e-5 at output,
//                   threshold 9.9e-4)
//  K6 final_dot  : y partials = out_flat . out_w[c,:]  (268 MB nt stream, HBM
//                  floor ~43us — the structural floor of this problem)
//  K7 finalize   : reduce partials + bias + softmax -> d_out[32]

namespace {
constexpr int  kN    = 8192;
constexpr int  kE    = 262144;
constexpr int  kTotE = kE + kN;          // 270336 (self loops appended)
constexpr long kK    = 2097152;          // N * H * C
constexpr int  kNBF  = 2048;             // final-dot blocks (1024 k each, exact)
}

typedef float vfloat4 __attribute__((ext_vector_type(4)));  // native vec for nt loads

static __device__ __forceinline__ ushort f2bf(float f) {  // RNE f32->bf16
  unsigned u = __float_as_uint(f);
  return (ushort)((u + 0x7FFFu + ((u >> 16) & 1u)) >> 16);
}
static __device__ __forceinline__ float bf2f(ushort b) {
  return __uint_as_float(((unsigned)b) << 16);
}

// ---------------- K1: xh = x @ lin_w^T  (M=8192, N=256, K=256) ----------------
__global__ __launch_bounds__(256) void gemm_xh(const float* __restrict__ x,
                                               const float* __restrict__ lw,
                                               float* __restrict__ xh,
                                               ushort* __restrict__ xh_bf) {
  __shared__ float As[16][68];
  __shared__ float Bs[16][68];
  const int t  = threadIdx.x;
  const int tx = t & 15, ty = t >> 4;
  const int rowBase = blockIdx.x * 64;
  const int colBase = blockIdx.y * 64;
  const int lr = t >> 2;
  const int lk = (t & 3) * 4;

  float acc[4][4] = {};
  for (int kc = 0; kc < 256; kc += 16) {
    float4 av = *(const float4*)(x  + (long)(rowBase + lr) * 256 + kc + lk);
    float4 bv = *(const float4*)(lw + (long)(colBase + lr) * 256 + kc + lk);
    __syncthreads();
    As[lk + 0][lr] = av.x; As[lk + 1][lr] = av.y; As[lk + 2][lr] = av.z; As[lk + 3][lr] = av.w;
    Bs[lk + 0][lr] = bv.x; Bs[lk + 1][lr] = bv.y; Bs[lk + 2][lr] = bv.z; Bs[lk + 3][lr] = bv.w;
    __syncthreads();
#pragma unroll
    for (int k = 0; k < 16; k++) {
      float4 a4 = *(const float4*)(&As[k][ty * 4]);
      float4 b4 = *(const float4*)(&Bs[k][tx * 4]);
      float aa[4] = {a4.x, a4.y, a4.z, a4.w};
      float bb[4] = {b4.x, b4.y, b4.z, b4.w};
#pragma unroll
      for (int i = 0; i < 4; i++)
#pragma unroll
        for (int j = 0; j < 4; j++) acc[i][j] += aa[i] * bb[j];
    }
  }
#pragma unroll
  for (int i = 0; i < 4; i++) {
    const long row = rowBase + ty * 4 + i;
    float4 o = make_float4(acc[i][0], acc[i][1], acc[i][2], acc[i][3]);
    *(float4*)(xh + row * 256 + colBase + tx * 4) = o;
    ushort4 ob = make_ushort4(f2bf(o.x), f2bf(o.y), f2bf(o.z), f2bf(o.w));
    *(ushort4*)(xh_bf + row * 256 + colBase + tx * 4) = ob;
  }
}

// ------------- K2: per-(node,head) attention dots + degree histogram -------------
__global__ __launch_bounds__(256) void att_deg(const float* __restrict__ xh,
                                               const float* __restrict__ att_s,
                                               const float* __restrict__ att_d,
                                               const int* __restrict__ ei,
                                               float* __restrict__ a_src,
                                               float* __restrict__ a_dst,
                                               int* __restrict__ cnt) {
  const int n = blockIdx.x, t = threadIdx.x;  // t = h*32 + c
  float v = xh[(long)n * 256 + t];
  float s = v * att_s[t];
  float d = v * att_d[t];
#pragma unroll
  for (int off = 16; off; off >>= 1) {
    s += __shfl_down(s, off, 32);
    d += __shfl_down(d, off, 32);
  }
  if ((t & 31) == 0) {
    a_src[n * 8 + (t >> 5)] = s;
    a_dst[n * 8 + (t >> 5)] = d;
  }
  // merged degree histogram (cnt pre-zeroed by memsetAsync; self-loop added in scan)
  const int gid = n * 256 + t;
  if (gid < kE) atomicAdd(&cnt[ei[kE + gid]], 1);  // ei[1][e] = dst
}

// ---------------- K3: single-block exclusive scan (+1 self-loop each) ----------------
__global__ __launch_bounds__(1024) void scan_cnt(const int* __restrict__ cnt,
                                                 int* __restrict__ rowptr,
                                                 int* __restrict__ wpos) {
  __shared__ int s[1024];
  const int t = threadIdx.x;
  int v[8]; int sum = 0;
#pragma unroll
  for (int q = 0; q < 8; q++) { v[q] = cnt[t * 8 + q] + 1; sum += v[q]; }  // +1 self-loop
  s[t] = sum;
  __syncthreads();
  for (int off = 1; off < 1024; off <<= 1) {
    int add = (t >= off) ? s[t - off] : 0;
    __syncthreads();
    s[t] += add;
    __syncthreads();
  }
  int excl = s[t] - sum;
#pragma unroll
  for (int q = 0; q < 8; q++) {
    rowptr[t * 8 + q] = excl;
    wpos[t * 8 + q]   = excl;
    excl += v[q];
  }
  if (t == 1023) rowptr[kN] = s[1023];
}

// ---------------- K4: bucket edges by dst + per-edge 8-head weights ----------------
__global__ __launch_bounds__(256) void scatter_csr(const int* __restrict__ ei,
                                                   const float* __restrict__ a_src,
                                                   const float* __restrict__ a_dst,
                                                   int* __restrict__ wpos,
                                                   int* __restrict__ csr,
                                                   float* __restrict__ w8) {
  int idx = blockIdx.x * 256 + threadIdx.x;
  if (idx >= kTotE) return;
  int s, d;
  if (idx < kE) { s = ei[idx]; d = ei[kE + idx]; }
  else          { s = idx - kE; d = s; }
  int pos = atomicAdd(&wpos[d], 1);
  csr[pos] = s;
  float4 s0 = *(const float4*)(a_src + s * 8);
  float4 s1 = *(const float4*)(a_src + s * 8 + 4);
  float4 d0 = *(const float4*)(a_dst + d * 8);
  float4 d1 = *(const float4*)(a_dst + d * 8 + 4);
  float e[8] = {s0.x + d0.x, s0.y + d0.y, s0.z + d0.z, s0.w + d0.w,
                s1.x + d1.x, s1.y + d1.y, s1.z + d1.z, s1.w + d1.w};
  float w[8];
#pragma unroll
  for (int h = 0; h < 8; h++) {
    float ee = (e[h] > 0.f) ? e[h] : 0.2f * e[h];   // leaky_relu(0.2)
    w[h] = __expf(ee);                              // |e| <~ 5, no max-sub needed
  }
  float4* wp = (float4*)(w8 + (long)pos * 8);
  wp[0] = make_float4(w[0], w[1], w[2], w[3]);
  wp[1] = make_float4(w[4], w[5], w[6], w[7]);
}

// ---------- K5: weighted gather aggregation (bf16 gathers, unroll x8) ----------
__global__ __launch_bounds__(256) void agg_kernel(const ushort* __restrict__ xb,
                                                  const float* __restrict__ w8,
                                                  const int* __restrict__ rowptr,
                                                  const int* __restrict__ csr,
                                                  const float* __restrict__ bias,
                                                  float* __restrict__ out_flat) {
  const int i = blockIdx.x, t = threadIdx.x, h = t >> 5;
  const int beg = rowptr[i], end = rowptr[i + 1];
  float acc = 0.f, den = 0.f;
  int j = beg;
  for (; j + 8 <= end; j += 8) {
    int   s[8]; float w[8]; float f[8];
#pragma unroll
    for (int q = 0; q < 8; q++) s[q] = csr[j + q];
#pragma unroll
    for (int q = 0; q < 8; q++) w[q] = w8[(long)(j + q) * 8 + h];
#pragma unroll
    for (int q = 0; q < 8; q++) f[q] = bf2f(xb[(long)s[q] * 256 + t]);
#pragma unroll
    for (int q = 0; q < 8; q++) { den += w[q]; acc += w[q] * f[q]; }
  }
  for (; j < end; j++) {
    int s0 = csr[j];
    float w0 = w8[(long)j * 8 + h];
    den += w0;
    acc += w0 * bf2f(xb[(long)s0 * 256 + t]);
  }
  out_flat[(long)i * 256 + t] = acc / den + bias[t];
}

// ---------------- K6: y partials = out_flat . out_w rows (268 MB nt stream) ----------------
__global__ __launch_bounds__(256) void final_dot(const float* __restrict__ of,
                                                 const float* __restrict__ w,
                                                 float* __restrict__ part) {
  const int t = threadIdx.x, b = blockIdx.x;
  const long k = (long)b * 1024 + t * 4;
  float4 f = *(const float4*)(of + k);
  float acc[32];
#pragma unroll
  for (int c = 0; c < 32; c++) {
    vfloat4 wv = __builtin_nontemporal_load((const vfloat4*)(w + (long)c * kK + k));
    acc[c] = wv.x * f.x + wv.y * f.y + wv.z * f.z + wv.w * f.w;
  }
#pragma unroll
  for (int c = 0; c < 32; c++) {
    float v = acc[c];
    v += __shfl_down(v, 32, 64);
    v += __shfl_down(v, 16, 64);
    v += __shfl_down(v, 8, 64);
    v += __shfl_down(v, 4, 64);
    v += __shfl_down(v, 2, 64);
    v += __shfl_down(v, 1, 64);
    acc[c] = v;
  }
  __shared__ float s[4][32];
  const int lane = t & 63, wid = t >> 6;
  if (lane == 0) {
#pragma unroll
    for (int c = 0; c < 32; c++) s[wid][c] = acc[c];
  }
  __syncthreads();
  if (t < 32) part[b * 32 + t] = s[0][t] + s[1][t] + s[2][t] + s[3][t];
}

// ---------------- K7: reduce partials + bias + softmax ----------------
__global__ __launch_bounds__(1024) void finalize(const float* __restrict__ part,
                                                 const float* __restrict__ ob,
                                                 float* __restrict__ out) {
  __shared__ float s[32][33];
  const int t = threadIdx.x;
  const int c = t & 31, r = t >> 5;
  float sum = 0.f;
  for (int i = r; i < kNBF; i += 32) sum += part[i * 32 + c];
  s[c][r] = sum;
  __syncthreads();
  if (t < 32) {
    float y = ob[t];
#pragma unroll
    for (int r2 = 0; r2 < 32; r2++) y += s[t][r2];
    float m = y;
#pragma unroll
    for (int off = 16; off; off >>= 1) m = fmaxf(m, __shfl_xor(m, off, 32));
    float e = __expf(y - m);
    float d = e;
#pragma unroll
    for (int off = 16; off; off >>= 1) d += __shfl_xor(d, off, 32);
    out[t] = e / d;
  }
}

extern "C" void kernel_launch(void* const* d_in, const int* in_sizes, int n_in,
                              void* d_out, int out_size, void* d_ws, size_t ws_size,
                              hipStream_t stream) {
  (void)in_sizes; (void)n_in; (void)out_size; (void)ws_size;
  const float* x     = (const float*)d_in[0];
  const int*   ei    = (const int*)  d_in[1];
  const float* lin_w = (const float*)d_in[2];
  const float* att_s = (const float*)d_in[3];
  const float* att_d = (const float*)d_in[4];
  const float* bias  = (const float*)d_in[5];
  const float* out_w = (const float*)d_in[6];
  const float* out_b = (const float*)d_in[7];
  float* out = (float*)d_out;

  // workspace layout (~31 MB)
  float*  xh       = (float*)d_ws;
  float*  out_flat = xh + kK;
  float*  a_src    = out_flat + kK;
  float*  a_dst    = a_src + kN * 8;
  float*  part     = a_dst + kN * 8;
  float*  w8       = part + (long)kNBF * 32;
  ushort* xh_bf    = (ushort*)(w8 + (long)kTotE * 8);
  int*    cnt      = (int*)(xh_bf + kK);
  int*    rowptr   = cnt + kN;
  int*    wpos     = rowptr + (kN + 1);
  int*    csr      = wpos + kN;

  (void)hipMemsetAsync(cnt, 0, kN * sizeof(int), stream);
  gemm_xh    <<<dim3(128, 4), 256, 0, stream>>>(x, lin_w, xh, xh_bf);
  att_deg    <<<kN, 256, 0, stream>>>(xh, att_s, att_d, ei, a_src, a_dst, cnt);
  scan_cnt   <<<1, 1024, 0, stream>>>(cnt, rowptr, wpos);
  scatter_csr<<<(kTotE + 255) / 256, 256, 0, stream>>>(ei, a_src, a_dst, wpos, csr, w8);
  agg_kernel <<<kN, 256, 0, stream>>>(xh_bf, w8, rowptr, csr, bias, out_flat);
  final_dot  <<<kNBF, 256, 0, stream>>>(out_flat, out_w, part);
  finalize   <<<1, 1024, 0, stream>>>(part, out_b, out);
}